// Round 5
// baseline (921.772 us; speedup 1.0000x reference)
//
#include <hip/hip_runtime.h>

#define BN 64
#define CN 32
#define HEADSN 8
#define HDN 4
#define LN 6400
#define CL (CN*LN)   // 204800

// ---------- helpers ----------

__device__ __forceinline__ unsigned fenc(float f){
  unsigned u = __float_as_uint(f);
  return (u & 0x80000000u) ? ~u : (u | 0x80000000u);
}
__device__ __forceinline__ float fdec(unsigned u){
  unsigned v = (u & 0x80000000u) ? (u & 0x7FFFFFFFu) : ~u;
  return __uint_as_float(v);
}

// Butterfly-reduce 32 per-thread values across the 64 lanes of a wave.
template<bool MAXOP>
__device__ __forceinline__ float bfly32(const float* in, int lane, int* chOut){
  const bool h0 = (lane & 1)  != 0, h1 = (lane & 2)  != 0, h2 = (lane & 4) != 0,
             h3 = (lane & 8)  != 0, h4 = (lane & 16) != 0;
  float a[16];
  #pragma unroll
  for (int i = 0; i < 16; ++i){
    float send = h0 ? in[i] : in[i+16];
    float keep = h0 ? in[i+16] : in[i];
    float recv = __shfl_xor(send, 1, 64);
    a[i] = MAXOP ? fmaxf(keep, recv) : keep + recv;
  }
  float b[8];
  #pragma unroll
  for (int i = 0; i < 8; ++i){
    float send = h1 ? a[i] : a[i+8];
    float keep = h1 ? a[i+8] : a[i];
    float recv = __shfl_xor(send, 2, 64);
    b[i] = MAXOP ? fmaxf(keep, recv) : keep + recv;
  }
  float c[4];
  #pragma unroll
  for (int i = 0; i < 4; ++i){
    float send = h2 ? b[i] : b[i+4];
    float keep = h2 ? b[i+4] : b[i];
    float recv = __shfl_xor(send, 4, 64);
    c[i] = MAXOP ? fmaxf(keep, recv) : keep + recv;
  }
  float d[2];
  #pragma unroll
  for (int i = 0; i < 2; ++i){
    float send = h3 ? c[i] : c[i+2];
    float keep = h3 ? c[i+2] : c[i];
    float recv = __shfl_xor(send, 8, 64);
    d[i] = MAXOP ? fmaxf(keep, recv) : keep + recv;
  }
  float e;
  {
    float send = h4 ? d[0] : d[1];
    float keep = h4 ? d[1] : d[0];
    float recv = __shfl_xor(send, 16, 64);
    e = MAXOP ? fmaxf(keep, recv) : keep + recv;
  }
  {
    float recv = __shfl_xor(e, 32, 64);
    e = MAXOP ? fmaxf(e, recv) : e + recv;
  }
  *chOut = (h0?16:0)|(h1?8:0)|(h2?4:0)|(h3?2:0)|(h4?1:0);
  return e;
}

__device__ __forceinline__ float bfly16_sum(const float* in, int lane, int* chOut){
  const bool h0 = (lane & 1) != 0, h1 = (lane & 2) != 0, h2 = (lane & 4) != 0,
             h3 = (lane & 8) != 0;
  float a[8];
  #pragma unroll
  for (int i = 0; i < 8; ++i){
    float send = h0 ? in[i] : in[i+8];
    float keep = h0 ? in[i+8] : in[i];
    float recv = __shfl_xor(send, 1, 64);
    a[i] = keep + recv;
  }
  float b[4];
  #pragma unroll
  for (int i = 0; i < 4; ++i){
    float send = h1 ? a[i] : a[i+4];
    float keep = h1 ? a[i+4] : a[i];
    float recv = __shfl_xor(send, 2, 64);
    b[i] = keep + recv;
  }
  float c[2];
  #pragma unroll
  for (int i = 0; i < 2; ++i){
    float send = h2 ? b[i] : b[i+2];
    float keep = h2 ? b[i+2] : b[i];
    float recv = __shfl_xor(send, 4, 64);
    c[i] = keep + recv;
  }
  float e;
  {
    float send = h3 ? c[0] : c[1];
    float keep = h3 ? c[1] : c[0];
    float recv = __shfl_xor(send, 8, 64);
    e = keep + recv;
  }
  e += __shfl_xor(e, 16, 64);
  e += __shfl_xor(e, 32, 64);
  *chOut = (h0?8:0)|(h1?4:0)|(h2?2:0)|(h3?1:0);
  return e;
}

// ---------- K1: LA reduce  attn[b,h,d,e] = sum_l k_hat[l,d] * v[l,e] ----------
__global__ __launch_bounds__(256, 4) void k_la_reduce(const float* __restrict__ rgb,
                                                      const float* __restrict__ Wqkv,
                                                      float* __restrict__ la_attn){
  __shared__ float2 xs2[256*17];
  const int b = blockIdx.y, l0 = blockIdx.x*256, tid = threadIdx.x;
  const float* xg = rgb + (size_t)b*CL + l0;
  #pragma unroll
  for (int c2 = 0; c2 < 16; ++c2){
    float e0 = xg[(2*c2)*LN + tid];
    float e1 = xg[(2*c2+1)*LN + tid];
    xs2[tid*17 + c2] = make_float2(e0, e1);
  }
  __syncthreads();
  const int wave = __builtin_amdgcn_readfirstlane(tid >> 6);
  const int lane = tid & 63;
  const float* Wk = Wqkv + (32 + wave*8)*32;
  const float* Wv = Wqkv + (64 + wave*8)*32;
  float acc[32];
  #pragma unroll
  for (int i = 0; i < 32; ++i) acc[i] = 0.f;
  for (int it = 0; it < 4; ++it){
    const int ll = it*64 + lane;
    float xv[32];
    #pragma unroll
    for (int c2 = 0; c2 < 16; ++c2){
      float2 t = xs2[ll*17 + c2];
      xv[2*c2] = t.x; xv[2*c2+1] = t.y;
    }
    float kk[8], vv[8];
    #pragma unroll
    for (int r = 0; r < 8; ++r){ kk[r] = 0.f; vv[r] = 0.f; }
    #pragma unroll
    for (int c = 0; c < 32; ++c){
      #pragma unroll
      for (int r = 0; r < 8; ++r){
        kk[r] = fmaf(Wk[r*32 + c], xv[c], kk[r]);
        vv[r] = fmaf(Wv[r*32 + c], xv[c], vv[r]);
      }
    }
    #pragma unroll
    for (int hh = 0; hh < 2; ++hh){
      const float* k = kk + hh*4;
      const float* v = vv + hh*4;
      float rn = rsqrtf(k[0]*k[0] + k[1]*k[1] + k[2]*k[2] + k[3]*k[3]);
      #pragma unroll
      for (int d = 0; d < 4; ++d){
        float kn = k[d]*rn;
        #pragma unroll
        for (int e = 0; e < 4; ++e)
          acc[hh*16 + d*4 + e] = fmaf(kn, v[e], acc[hh*16 + d*4 + e]);
      }
    }
  }
  int ch;
  float s = bfly32<false>(acc, lane, &ch);
  if (lane < 32) atomicAdd(la_attn + b*128 + wave*32 + ch, s);
}

// ---------- K3: XCA reduce  Sqk[16], Sqq[4], Skk[4] per (b,h) ----------
__global__ __launch_bounds__(256, 4) void k_xa_reduce(const float* __restrict__ freq,
                                                      const float* __restrict__ Wqkv,
                                                      float* __restrict__ xa_sums){
  __shared__ float2 xs2[256*17];
  const int b = blockIdx.y, l0 = blockIdx.x*256, tid = threadIdx.x;
  const float* xg = freq + (size_t)b*CL + l0;
  #pragma unroll
  for (int c2 = 0; c2 < 16; ++c2){
    float e0 = xg[(2*c2)*LN + tid];
    float e1 = xg[(2*c2+1)*LN + tid];
    xs2[tid*17 + c2] = make_float2(e0, e1);
  }
  __syncthreads();
  const int wave = __builtin_amdgcn_readfirstlane(tid >> 6);
  const int lane = tid & 63;
  const float* Wq = Wqkv + (0  + wave*8)*32;
  const float* Wk = Wqkv + (32 + wave*8)*32;
  float acc[48];
  #pragma unroll
  for (int i = 0; i < 48; ++i) acc[i] = 0.f;
  for (int it = 0; it < 4; ++it){
    const int ll = it*64 + lane;
    float xv[32];
    #pragma unroll
    for (int c2 = 0; c2 < 16; ++c2){
      float2 t = xs2[ll*17 + c2];
      xv[2*c2] = t.x; xv[2*c2+1] = t.y;
    }
    float qq[8], kk[8];
    #pragma unroll
    for (int r = 0; r < 8; ++r){ qq[r] = 0.f; kk[r] = 0.f; }
    #pragma unroll
    for (int c = 0; c < 32; ++c){
      #pragma unroll
      for (int r = 0; r < 8; ++r){
        qq[r] = fmaf(Wq[r*32 + c], xv[c], qq[r]);
        kk[r] = fmaf(Wk[r*32 + c], xv[c], kk[r]);
      }
    }
    #pragma unroll
    for (int hh = 0; hh < 2; ++hh){
      const float* q = qq + hh*4;
      const float* k = kk + hh*4;
      const int base = hh*24;
      #pragma unroll
      for (int d = 0; d < 4; ++d){
        #pragma unroll
        for (int e = 0; e < 4; ++e)
          acc[base + d*4 + e] = fmaf(q[d], k[e], acc[base + d*4 + e]);
      }
      #pragma unroll
      for (int d = 0; d < 4; ++d) acc[base + 16 + d] = fmaf(q[d], q[d], acc[base + 16 + d]);
      #pragma unroll
      for (int e = 0; e < 4; ++e) acc[base + 20 + e] = fmaf(k[e], k[e], acc[base + 20 + e]);
    }
  }
  float* dst = xa_sums + b*192 + wave*48;
  int ch;
  float s0 = bfly32<false>(acc, lane, &ch);
  if (lane < 32) atomicAdd(dst + ch, s0);
  int ch2;
  float s1 = bfly16_sum(acc + 32, lane, &ch2);
  if (lane < 16) atomicAdd(dst + 32 + ch2, s1);
}

// ---------- K3b: fold XCA softmax into a single 32x32 matrix per b ----------
// f2 = Wp·(A·(Wv·x)) + bp == (Wp·A·Wv)·x + bp   ->  M2[b] = Wp·A·Wv
__global__ __launch_bounds__(64) void k_fold(const float* __restrict__ xa_sums,
                                             const float* __restrict__ temp,
                                             const float* __restrict__ Wqkv,
                                             const float* __restrict__ Wp,
                                             float* __restrict__ M2){
  __shared__ float attn_s[128];
  const int b = blockIdx.x, t = threadIdx.x;
  if (t < 32){
    const int h = t >> 2, d = t & 3;
    const float* xss = xa_sums + b*192 + h*24;
    const float tmp = temp[h];
    const float nq = fmaxf(sqrtf(xss[16 + d]), 1e-12f);
    float lg[4]; float m = -1e30f;
    #pragma unroll
    for (int e = 0; e < 4; ++e){
      float nk = fmaxf(sqrtf(xss[20 + e]), 1e-12f);
      lg[e] = xss[d*4 + e] * tmp / (nq*nk);
      m = fmaxf(m, lg[e]);
    }
    float Z = 0.f;
    #pragma unroll
    for (int e = 0; e < 4; ++e){ lg[e] = __expf(lg[e] - m); Z += lg[e]; }
    float iZ = 1.f/Z;
    #pragma unroll
    for (int e = 0; e < 4; ++e) attn_s[h*16 + d*4 + e] = lg[e]*iZ;
  }
  __syncthreads();
  if (t < 32){
    const int c = t;                          // column of M2
    const float* Wv = Wqkv + 64*32;
    float tmpv[32];                           // (A·Wv)[:, c]
    #pragma unroll
    for (int k = 0; k < 32; ++k){
      const int h = k >> 2, d = k & 3;
      float s = 0.f;
      #pragma unroll
      for (int e = 0; e < 4; ++e)
        s = fmaf(attn_s[h*16 + d*4 + e], Wv[(h*4 + e)*32 + c], s);
      tmpv[k] = s;
    }
    float out[32];
    #pragma unroll
    for (int r = 0; r < 32; ++r) out[r] = 0.f;
    #pragma unroll
    for (int k = 0; k < 32; ++k){
      #pragma unroll
      for (int r = 0; r < 32; ++r)
        out[r] = fmaf(Wp[r*32 + k], tmpv[k], out[r]);
    }
    #pragma unroll
    for (int r = 0; r < 32; ++r) M2[b*1024 + r*32 + c] = out[r];
  }
}

// ---------- K2: LA finalize -> f1, + fused channel sum/max stats ----------
// v and q computed in ONE 64-accumulator pass over x; own v stays in registers;
// LDS only for the dconv neighbor tile; projection in accumulator-array form.
__global__ __launch_bounds__(256, 4) void k_la_final(const float* __restrict__ rgb,
    const float* __restrict__ Wqkv, const float* __restrict__ la_attn,
    const float* __restrict__ dconv_w, const float* __restrict__ Wp,
    const float* __restrict__ bp, float* __restrict__ f1,
    float* __restrict__ sum1, unsigned* __restrict__ max1e){
  __shared__ float2 vsh2[264*17];        // 35.9 KB -> 4 blocks/CU
  const int b = blockIdx.y, l0 = blockIdx.x*256, tid = threadIdx.x;
  const int l = l0 + tid, lane = tid & 63;
  const float* xg = rgb + (size_t)b*CL;
  float x[32];
  #pragma unroll
  for (int c = 0; c < 32; ++c) x[c] = xg[c*LN + l];
  float v[32], q[32];
  #pragma unroll
  for (int r = 0; r < 32; ++r){ v[r] = 0.f; q[r] = 0.f; }
  {
    const float* Wq = Wqkv;
    const float* Wv = Wqkv + 64*32;
    #pragma unroll
    for (int c = 0; c < 32; ++c){
      #pragma unroll
      for (int r = 0; r < 32; ++r){
        v[r] = fmaf(Wv[r*32 + c], x[c], v[r]);
        q[r] = fmaf(Wq[r*32 + c], x[c], q[r]);
      }
    }
  }
  #pragma unroll
  for (int c2 = 0; c2 < 16; ++c2)
    vsh2[(tid+4)*17 + c2] = make_float2(v[2*c2], v[2*c2+1]);
  // halo v: 8 pixels x 16 float2-channels, one (p,c2) pair per thread (tid<128)
  if (tid < 128){
    const int p = tid >> 4, c2 = tid & 15;
    const int hl  = (p < 4) ? (l0 - 4 + p) : (l0 + 252 + p);
    const int pos = (p < 4) ? p : (256 + p);
    float2 vh = make_float2(0.f, 0.f);
    if (hl >= 0 && hl < LN){
      const float* W0 = Wqkv + (64 + 2*c2)*32;
      #pragma unroll 8
      for (int cc = 0; cc < 32; ++cc){
        float xv = xg[cc*LN + hl];
        vh.x = fmaf(W0[cc],      xv, vh.x);
        vh.y = fmaf(W0[32 + cc], xv, vh.y);
      }
    }
    vsh2[pos*17 + c2] = vh;
  }
  __syncthreads();
  float y[32];
  #pragma unroll
  for (int h = 0; h < 8; ++h){
    float q0 = q[h*4], q1 = q[h*4+1], q2 = q[h*4+2], q3 = q[h*4+3];
    const float rnq = rsqrtf(q0*q0 + q1*q1 + q2*q2 + q3*q3);
    q0 *= rnq; q1 *= rnq; q2 *= rnq; q3 *= rnq;
    const float* at = la_attn + b*128 + h*16;   // uniform -> s_load
    float o[4]; float ss = 0.f;
    #pragma unroll
    for (int e = 0; e < 4; ++e){
      float t = 0.f;
      t = fmaf(q0, at[e],      t);
      t = fmaf(q1, at[4 + e],  t);
      t = fmaf(q2, at[8 + e],  t);
      t = fmaf(q3, at[12 + e], t);
      o[e] = fmaf(0.31830988618379067f, t, 0.5f*v[h*4 + e]);
      ss = fmaf(o[e], o[e], ss);
    }
    const float rno = rsqrtf(ss);
    float dc[4] = {0.f, 0.f, 0.f, 0.f};
    #pragma unroll
    for (int j = 0; j < 9; ++j){
      const float w = dconv_w[h*9 + j];
      const float2 p0 = vsh2[(tid + j)*17 + h*2];
      const float2 p1 = vsh2[(tid + j)*17 + h*2 + 1];
      dc[0] = fmaf(w, p0.x, dc[0]);
      dc[1] = fmaf(w, p0.y, dc[1]);
      dc[2] = fmaf(w, p1.x, dc[2]);
      dc[3] = fmaf(w, p1.y, dc[3]);
    }
    #pragma unroll
    for (int e = 0; e < 4; ++e) y[h*4 + e] = fmaf(o[e], rno, dc[e]);
  }
  // projection in accumulator-array form (32 independent chains)
  float vals[32];
  #pragma unroll
  for (int r = 0; r < 32; ++r) vals[r] = bp[r];
  #pragma unroll
  for (int c = 0; c < 32; ++c){
    #pragma unroll
    for (int r = 0; r < 32; ++r) vals[r] = fmaf(Wp[r*32 + c], y[c], vals[r]);
  }
  float* f1p = f1 + (size_t)b*CL + l;
  #pragma unroll
  for (int r = 0; r < 32; ++r) f1p[r*LN] = vals[r];
  int ch;
  float s = bfly32<false>(vals, lane, &ch);
  float m = bfly32<true >(vals, lane, &ch);
  if (lane < 32){
    atomicAdd(&sum1[b*32 + ch], s);
    atomicMax(&max1e[b*32 + ch], fenc(m));
  }
}

// ---------- K4: XCA finalize -> f2 = M2[b]·x + bp, + fused stats ----------
__global__ __launch_bounds__(256, 4) void k_xa_final(const float* __restrict__ freq,
    const float* __restrict__ M2, const float* __restrict__ bp,
    float* __restrict__ f2, float* __restrict__ sum2, unsigned* __restrict__ max2e){
  const int b = blockIdx.y, l0 = blockIdx.x*256, tid = threadIdx.x;
  const int l = l0 + tid, lane = tid & 63;
  const float* xg = freq + (size_t)b*CL;
  float x[32];
  #pragma unroll
  for (int c = 0; c < 32; ++c) x[c] = xg[c*LN + l];
  const float* M = M2 + b*1024;            // uniform -> s_load
  float vals[32];
  #pragma unroll
  for (int r = 0; r < 32; ++r) vals[r] = bp[r];
  #pragma unroll
  for (int c = 0; c < 32; ++c){
    #pragma unroll
    for (int r = 0; r < 32; ++r) vals[r] = fmaf(M[r*32 + c], x[c], vals[r]);
  }
  float* f2p = f2 + (size_t)b*CL + l;
  #pragma unroll
  for (int r = 0; r < 32; ++r) f2p[r*LN] = vals[r];
  int ch;
  float s = bfly32<false>(vals, lane, &ch);
  float m = bfly32<true >(vals, lane, &ch);
  if (lane < 32){
    atomicAdd(&sum2[b*32 + ch], s);
    atomicMax(&max2e[b*32 + ch], fenc(m));
  }
}

// ---------- K5: channel vectors, cross softmax weights w1,w2 ----------
__global__ __launch_bounds__(64) void k_vec(
  const float* __restrict__ sum1, const unsigned* __restrict__ max1e,
  const float* __restrict__ sum2, const unsigned* __restrict__ max2e,
  const float* __restrict__ a1w, const float* __restrict__ a1b,
  const float* __restrict__ m1w, const float* __restrict__ m1b,
  const float* __restrict__ a2w, const float* __restrict__ a2b,
  const float* __restrict__ m2w, const float* __restrict__ m2b,
  const float* __restrict__ a11w, const float* __restrict__ a11b,
  const float* __restrict__ m11w, const float* __restrict__ m11b,
  const float* __restrict__ a22w, const float* __restrict__ a22b,
  const float* __restrict__ m22w, const float* __restrict__ m22b,
  float* __restrict__ w1o, float* __restrict__ w2o){
  __shared__ float avg1[32], mx1[32], avg2[32], mx2[32];
  __shared__ float h_a1[16], h_m1[16], h_a2[16], h_m2[16];
  __shared__ float a1v[32], a2v[32];
  const int b = blockIdx.x, t = threadIdx.x;
  if (t < 32){
    avg1[t] = sum1[b*32 + t] * (1.f/6400.f);
    mx1[t]  = fdec(max1e[b*32 + t]);
    avg2[t] = sum2[b*32 + t] * (1.f/6400.f);
    mx2[t]  = fdec(max2e[b*32 + t]);
  }
  __syncthreads();
  if (t < 16){
    float s1 = a1b[t], s2 = m1b[t], s3 = a2b[t], s4 = m2b[t];
    for (int c = 0; c < 32; ++c){
      s1 = fmaf(avg1[c], a1w[t*32 + c], s1);
      s2 = fmaf(mx1[c],  m1w[t*32 + c], s2);
      s3 = fmaf(avg2[c], a2w[t*32 + c], s3);
      s4 = fmaf(mx2[c],  m2w[t*32 + c], s4);
    }
    h_a1[t] = fmaxf(s1, 0.f); h_m1[t] = fmaxf(s2, 0.f);
    h_a2[t] = fmaxf(s3, 0.f); h_m2[t] = fmaxf(s4, 0.f);
  }
  __syncthreads();
  if (t < 32){
    float v1 = a11b[t] + m11b[t];
    float v2 = a22b[t] + m22b[t];
    for (int k = 0; k < 16; ++k){
      v1 += h_a1[k]*a11w[t*16 + k] + h_m1[k]*m11w[t*16 + k];
      v2 += h_a2[k]*a22w[t*16 + k] + h_m2[k]*m22w[t*16 + k];
    }
    a1v[t] = v1; a2v[t] = v2;
  }
  __syncthreads();
  if (t < 32){
    float s = a1v[t], m = -1e30f;
    for (int d = 0; d < 32; ++d) m = fmaxf(m, s*a2v[d]);
    float Z = 0.f;
    for (int d = 0; d < 32; ++d) Z += __expf(s*a2v[d] - m);
    float iZ = 1.f/Z;
    for (int d = 0; d < 32; ++d) w1o[b*1024 + t*32 + d] = __expf(s*a2v[d] - m)*iZ;
    float s2 = a2v[t]; m = -1e30f;
    for (int d = 0; d < 32; ++d) m = fmaxf(m, s2*a1v[d]);
    Z = 0.f;
    for (int d = 0; d < 32; ++d) Z += __expf(s2*a1v[d] - m);
    iZ = 1.f/Z;
    for (int d = 0; d < 32; ++d) w2o[b*1024 + t*32 + d] = __expf(s2*a1v[d] - m)*iZ;
  }
}

// ---------- K6: mixing + channel mean/max pooling (ILP accumulator form) ----------
__global__ __launch_bounds__(256, 4) void k_mix(const float* __restrict__ f1,
    const float* __restrict__ f2, const float* __restrict__ w1,
    const float* __restrict__ w2, float* __restrict__ pooled1,
    float* __restrict__ pooled2){
  const int b = blockIdx.y, l = blockIdx.x*256 + threadIdx.x;
  float fv[32], av[32];
  {
    const float* f1p = f1 + (size_t)b*CL + l;
    #pragma unroll
    for (int d = 0; d < 32; ++d) fv[d] = f1p[d*LN];
    const float* W = w1 + b*1024;
    #pragma unroll
    for (int c = 0; c < 32; ++c) av[c] = 0.f;
    #pragma unroll
    for (int d = 0; d < 32; ++d){
      #pragma unroll
      for (int c = 0; c < 32; ++c) av[c] = fmaf(W[c*32 + d], fv[d], av[c]);
    }
    float s = 0.f, m = -1e30f;
    #pragma unroll
    for (int c = 0; c < 32; ++c){ s += av[c]; m = fmaxf(m, av[c]); }
    pooled1[(size_t)b*2*LN + l]      = s*(1.f/32.f);
    pooled1[(size_t)b*2*LN + LN + l] = m;
  }
  {
    const float* f2p = f2 + (size_t)b*CL + l;
    #pragma unroll
    for (int d = 0; d < 32; ++d) fv[d] = f2p[d*LN];
    const float* W = w2 + b*1024;
    #pragma unroll
    for (int c = 0; c < 32; ++c) av[c] = 0.f;
    #pragma unroll
    for (int d = 0; d < 32; ++d){
      #pragma unroll
      for (int c = 0; c < 32; ++c) av[c] = fmaf(W[c*32 + d], fv[d], av[c]);
    }
    float s = 0.f, m = -1e30f;
    #pragma unroll
    for (int c = 0; c < 32; ++c){ s += av[c]; m = fmaxf(m, av[c]); }
    pooled2[(size_t)b*2*LN + l]      = s*(1.f/32.f);
    pooled2[(size_t)b*2*LN + LN + l] = m;
  }
}

// ---------- K7: conv3x3 -> relu -> conv3x3 -> softmax over L ----------
__global__ __launch_bounds__(256) void k_gate(const float* __restrict__ pooled1,
    const float* __restrict__ pooled2, const float* __restrict__ c1w,
    const float* __restrict__ c1b, const float* __restrict__ c2w,
    const float* __restrict__ c2b, float* __restrict__ g1, float* __restrict__ g2){
  __shared__ float y1s[6400];
  __shared__ float red[8];
  const int b = blockIdx.y, t = blockIdx.x, tid = threadIdx.x;
  const float* src = (t == 0 ? pooled1 : pooled2) + (size_t)b*2*LN;
  float* dst = (t == 0 ? g1 : g2) + (size_t)b*LN;
  for (int i = tid; i < 6400; i += 256){
    const int yy = i/80, xx = i - yy*80;
    float a = c1b[0];
    #pragma unroll
    for (int ky = 0; ky < 3; ++ky){
      const int y2 = yy + ky - 1;
      if (y2 < 0 || y2 >= 80) continue;
      #pragma unroll
      for (int kx = 0; kx < 3; ++kx){
        const int x2 = xx + kx - 1;
        if (x2 < 0 || x2 >= 80) continue;
        const int j = y2*80 + x2;
        a = fmaf(src[j],        c1w[ky*3 + kx],     a);
        a = fmaf(src[6400 + j], c1w[9 + ky*3 + kx], a);
      }
    }
    y1s[i] = fmaxf(a, 0.f);
  }
  __syncthreads();
  float y2r[25]; float lmax = -1e30f;
  #pragma unroll
  for (int ii = 0; ii < 25; ++ii){
    const int i = tid + ii*256;
    const int yy = i/80, xx = i - yy*80;
    float a = c2b[0];
    #pragma unroll
    for (int ky = 0; ky < 3; ++ky){
      const int y2 = yy + ky - 1;
      if (y2 < 0 || y2 >= 80) continue;
      #pragma unroll
      for (int kx = 0; kx < 3; ++kx){
        const int x2 = xx + kx - 1;
        if (x2 < 0 || x2 >= 80) continue;
        a = fmaf(y1s[y2*80 + x2], c2w[ky*3 + kx], a);
      }
    }
    y2r[ii] = a; lmax = fmaxf(lmax, a);
  }
  #pragma unroll
  for (int off = 32; off >= 1; off >>= 1) lmax = fmaxf(lmax, __shfl_xor(lmax, off, 64));
  if ((tid & 63) == 0) red[tid >> 6] = lmax;
  __syncthreads();
  const float bmax = fmaxf(fmaxf(red[0], red[1]), fmaxf(red[2], red[3]));
  float lsum = 0.f;
  #pragma unroll
  for (int ii = 0; ii < 25; ++ii){
    float e = __expf(y2r[ii] - bmax);
    y2r[ii] = e; lsum += e;
  }
  #pragma unroll
  for (int off = 32; off >= 1; off >>= 1) lsum += __shfl_xor(lsum, off, 64);
  if ((tid & 63) == 0) red[4 + (tid >> 6)] = lsum;
  __syncthreads();
  const float inv = 1.f/(red[4] + red[5] + red[6] + red[7]);
  #pragma unroll
  for (int ii = 0; ii < 25; ++ii) dst[tid + ii*256] = y2r[ii]*inv;
}

// ---------- K8: out = f1*(1+g1) + f2*(1+g2) ----------
__global__ __launch_bounds__(256) void k_final(const float* __restrict__ f1,
    const float* __restrict__ f2, const float* __restrict__ g1,
    const float* __restrict__ g2, float* __restrict__ out){
  const int i = blockIdx.x*256 + threadIdx.x;
  const int flat = i*4;
  const int b = flat / CL;
  const int rem = flat - b*CL;
  const int l = rem % LN;
  const float4 a  = *(const float4*)(f1 + flat);
  const float4 c  = *(const float4*)(f2 + flat);
  const float4 ga = *(const float4*)(g1 + b*LN + l);
  const float4 gc = *(const float4*)(g2 + b*LN + l);
  float4 o;
  o.x = fmaf(a.x, ga.x, a.x) + fmaf(c.x, gc.x, c.x);
  o.y = fmaf(a.y, ga.y, a.y) + fmaf(c.y, gc.y, c.y);
  o.z = fmaf(a.z, ga.z, a.z) + fmaf(c.z, gc.z, c.z);
  o.w = fmaf(a.w, ga.w, a.w) + fmaf(c.w, gc.w, c.w);
  *(float4*)(out + flat) = o;
}

// ---------- host ----------
extern "C" void kernel_launch(void* const* d_in, const int* in_sizes, int n_in,
                              void* d_out, int out_size, void* d_ws, size_t ws_size,
                              hipStream_t stream){
  const float* rgb     = (const float*)d_in[0];
  const float* freq    = (const float*)d_in[1];
  const float* la_qkv  = (const float*)d_in[2];
  const float* la_pw   = (const float*)d_in[3];
  const float* la_pb   = (const float*)d_in[4];
  const float* la_dw   = (const float*)d_in[5];
  const float* xa_qkv  = (const float*)d_in[6];
  const float* xa_temp = (const float*)d_in[7];
  const float* xa_pw   = (const float*)d_in[8];
  const float* xa_pb   = (const float*)d_in[9];
  const float* c1w     = (const float*)d_in[10];
  const float* c1b     = (const float*)d_in[11];
  const float* c2w     = (const float*)d_in[12];
  const float* c2b     = (const float*)d_in[13];

  float* ws = (float*)d_ws;
  size_t o = 0;
  float* f1      = ws + o; o += (size_t)BN*CL;
  float* f2      = ws + o; o += (size_t)BN*CL;
  float* la_attn = ws + o; o += BN*128;
  float* xa_sums = ws + o; o += BN*192;
  float* sum1    = ws + o; o += BN*32;
  unsigned* max1e = (unsigned*)(ws + o); o += BN*32;
  float* sum2    = ws + o; o += BN*32;
  unsigned* max2e = (unsigned*)(ws + o); o += BN*32;
  float* w1      = ws + o; o += BN*1024;
  float* w2      = ws + o; o += BN*1024;
  float* pooled1 = ws + o; o += (size_t)BN*2*LN;
  float* pooled2 = ws + o; o += (size_t)BN*2*LN;
  float* g1      = ws + o; o += (size_t)BN*LN;
  float* g2      = ws + o; o += (size_t)BN*LN;
  float* M2      = ws + o; o += (size_t)BN*1024;

  // zero the atomically-accumulated regions (la_attn .. max2e, contiguous)
  const size_t nz = (size_t)BN*128 + BN*192 + (size_t)BN*32*4;
  hipMemsetAsync(la_attn, 0, nz*sizeof(float), stream);

  k_la_reduce<<<dim3(25, BN), 256, 0, stream>>>(rgb, la_qkv, la_attn);
  k_xa_reduce<<<dim3(25, BN), 256, 0, stream>>>(freq, xa_qkv, xa_sums);
  k_fold     <<<BN, 64, 0, stream>>>(xa_sums, xa_temp, xa_qkv, xa_pw, M2);
  k_la_final <<<dim3(25, BN), 256, 0, stream>>>(rgb, la_qkv, la_attn, la_dw, la_pw, la_pb,
                                                f1, sum1, max1e);
  k_xa_final <<<dim3(25, BN), 256, 0, stream>>>(freq, M2, xa_pb, f2, sum2, max2e);
  k_vec<<<BN, 64, 0, stream>>>(sum1, max1e, sum2, max2e,
      (const float*)d_in[14], (const float*)d_in[15], (const float*)d_in[16], (const float*)d_in[17],
      (const float*)d_in[18], (const float*)d_in[19], (const float*)d_in[20], (const float*)d_in[21],
      (const float*)d_in[22], (const float*)d_in[23], (const float*)d_in[24], (const float*)d_in[25],
      (const float*)d_in[26], (const float*)d_in[27], (const float*)d_in[28], (const float*)d_in[29],
      w1, w2);
  k_mix  <<<dim3(25, BN), 256, 0, stream>>>(f1, f2, w1, w2, pooled1, pooled2);
  k_gate <<<dim3(2, BN), 256, 0, stream>>>(pooled1, pooled2, c1w, c1b, c2w, c2b, g1, g2);
  k_final<<<12800, 256, 0, stream>>>(f1, f2, g1, g2, (float*)d_out);
}

// Round 6
// 565.287 us; speedup vs baseline: 1.6306x; 1.6306x over previous
//
#include <hip/hip_runtime.h>

#define BN 64
#define CN 32
#define HEADSN 8
#define HDN 4
#define LN 6400
#define CL (CN*LN)   // 204800

// ---------- helpers ----------

__device__ __forceinline__ unsigned fenc(float f){
  unsigned u = __float_as_uint(f);
  return (u & 0x80000000u) ? ~u : (u | 0x80000000u);
}
__device__ __forceinline__ float fdec(unsigned u){
  unsigned v = (u & 0x80000000u) ? (u & 0x7FFFFFFFu) : ~u;
  return __uint_as_float(v);
}

// Butterfly-reduce 32 per-thread values across the 64 lanes of a wave.
template<bool MAXOP>
__device__ __forceinline__ float bfly32(const float* in, int lane, int* chOut){
  const bool h0 = (lane & 1)  != 0, h1 = (lane & 2)  != 0, h2 = (lane & 4) != 0,
             h3 = (lane & 8)  != 0, h4 = (lane & 16) != 0;
  float a[16];
  #pragma unroll
  for (int i = 0; i < 16; ++i){
    float send = h0 ? in[i] : in[i+16];
    float keep = h0 ? in[i+16] : in[i];
    float recv = __shfl_xor(send, 1, 64);
    a[i] = MAXOP ? fmaxf(keep, recv) : keep + recv;
  }
  float b[8];
  #pragma unroll
  for (int i = 0; i < 8; ++i){
    float send = h1 ? a[i] : a[i+8];
    float keep = h1 ? a[i+8] : a[i];
    float recv = __shfl_xor(send, 2, 64);
    b[i] = MAXOP ? fmaxf(keep, recv) : keep + recv;
  }
  float c[4];
  #pragma unroll
  for (int i = 0; i < 4; ++i){
    float send = h2 ? b[i] : b[i+4];
    float keep = h2 ? b[i+4] : b[i];
    float recv = __shfl_xor(send, 4, 64);
    c[i] = MAXOP ? fmaxf(keep, recv) : keep + recv;
  }
  float d[2];
  #pragma unroll
  for (int i = 0; i < 2; ++i){
    float send = h3 ? c[i] : c[i+2];
    float keep = h3 ? c[i+2] : c[i];
    float recv = __shfl_xor(send, 8, 64);
    d[i] = MAXOP ? fmaxf(keep, recv) : keep + recv;
  }
  float e;
  {
    float send = h4 ? d[0] : d[1];
    float keep = h4 ? d[1] : d[0];
    float recv = __shfl_xor(send, 16, 64);
    e = MAXOP ? fmaxf(keep, recv) : keep + recv;
  }
  {
    float recv = __shfl_xor(e, 32, 64);
    e = MAXOP ? fmaxf(e, recv) : e + recv;
  }
  *chOut = (h0?16:0)|(h1?8:0)|(h2?4:0)|(h3?2:0)|(h4?1:0);
  return e;
}

__device__ __forceinline__ float bfly16_sum(const float* in, int lane, int* chOut){
  const bool h0 = (lane & 1) != 0, h1 = (lane & 2) != 0, h2 = (lane & 4) != 0,
             h3 = (lane & 8) != 0;
  float a[8];
  #pragma unroll
  for (int i = 0; i < 8; ++i){
    float send = h0 ? in[i] : in[i+8];
    float keep = h0 ? in[i+8] : in[i];
    float recv = __shfl_xor(send, 1, 64);
    a[i] = keep + recv;
  }
  float b[4];
  #pragma unroll
  for (int i = 0; i < 4; ++i){
    float send = h1 ? a[i] : a[i+4];
    float keep = h1 ? a[i+4] : a[i];
    float recv = __shfl_xor(send, 2, 64);
    b[i] = keep + recv;
  }
  float c[2];
  #pragma unroll
  for (int i = 0; i < 2; ++i){
    float send = h2 ? b[i] : b[i+2];
    float keep = h2 ? b[i+2] : b[i];
    float recv = __shfl_xor(send, 4, 64);
    c[i] = keep + recv;
  }
  float e;
  {
    float send = h3 ? c[0] : c[1];
    float keep = h3 ? c[1] : c[0];
    float recv = __shfl_xor(send, 8, 64);
    e = keep + recv;
  }
  e += __shfl_xor(e, 16, 64);
  e += __shfl_xor(e, 32, 64);
  *chOut = (h0?8:0)|(h1?4:0)|(h2?2:0)|(h3?1:0);
  return e;
}

// ---------- K1: LA reduce  attn[b,h,d,e] = sum_l k_hat[l,d] * v[l,e] ----------
__global__ __launch_bounds__(256, 4) void k_la_reduce(const float* __restrict__ rgb,
                                                      const float* __restrict__ Wqkv,
                                                      float* __restrict__ la_attn){
  __shared__ float2 xs2[256*17];
  const int b = blockIdx.y, l0 = blockIdx.x*256, tid = threadIdx.x;
  const float* xg = rgb + (size_t)b*CL + l0;
  #pragma unroll
  for (int c2 = 0; c2 < 16; ++c2){
    float e0 = xg[(2*c2)*LN + tid];
    float e1 = xg[(2*c2+1)*LN + tid];
    xs2[tid*17 + c2] = make_float2(e0, e1);
  }
  __syncthreads();
  const int wave = __builtin_amdgcn_readfirstlane(tid >> 6);
  const int lane = tid & 63;
  const float* Wk = Wqkv + (32 + wave*8)*32;
  const float* Wv = Wqkv + (64 + wave*8)*32;
  float acc[32];
  #pragma unroll
  for (int i = 0; i < 32; ++i) acc[i] = 0.f;
  for (int it = 0; it < 4; ++it){
    const int ll = it*64 + lane;
    float xv[32];
    #pragma unroll
    for (int c2 = 0; c2 < 16; ++c2){
      float2 t = xs2[ll*17 + c2];
      xv[2*c2] = t.x; xv[2*c2+1] = t.y;
    }
    float kk[8], vv[8];
    #pragma unroll
    for (int r = 0; r < 8; ++r){ kk[r] = 0.f; vv[r] = 0.f; }
    #pragma unroll
    for (int c = 0; c < 32; ++c){
      #pragma unroll
      for (int r = 0; r < 8; ++r){
        kk[r] = fmaf(Wk[r*32 + c], xv[c], kk[r]);
        vv[r] = fmaf(Wv[r*32 + c], xv[c], vv[r]);
      }
    }
    #pragma unroll
    for (int hh = 0; hh < 2; ++hh){
      const float* k = kk + hh*4;
      const float* v = vv + hh*4;
      float rn = rsqrtf(k[0]*k[0] + k[1]*k[1] + k[2]*k[2] + k[3]*k[3]);
      #pragma unroll
      for (int d = 0; d < 4; ++d){
        float kn = k[d]*rn;
        #pragma unroll
        for (int e = 0; e < 4; ++e)
          acc[hh*16 + d*4 + e] = fmaf(kn, v[e], acc[hh*16 + d*4 + e]);
      }
    }
  }
  int ch;
  float s = bfly32<false>(acc, lane, &ch);
  if (lane < 32) atomicAdd(la_attn + b*128 + wave*32 + ch, s);
}

// ---------- K3: XCA reduce  Sqk[16], Sqq[4], Skk[4] per (b,h) ----------
__global__ __launch_bounds__(256, 4) void k_xa_reduce(const float* __restrict__ freq,
                                                      const float* __restrict__ Wqkv,
                                                      float* __restrict__ xa_sums){
  __shared__ float2 xs2[256*17];
  const int b = blockIdx.y, l0 = blockIdx.x*256, tid = threadIdx.x;
  const float* xg = freq + (size_t)b*CL + l0;
  #pragma unroll
  for (int c2 = 0; c2 < 16; ++c2){
    float e0 = xg[(2*c2)*LN + tid];
    float e1 = xg[(2*c2+1)*LN + tid];
    xs2[tid*17 + c2] = make_float2(e0, e1);
  }
  __syncthreads();
  const int wave = __builtin_amdgcn_readfirstlane(tid >> 6);
  const int lane = tid & 63;
  const float* Wq = Wqkv + (0  + wave*8)*32;
  const float* Wk = Wqkv + (32 + wave*8)*32;
  float acc[48];
  #pragma unroll
  for (int i = 0; i < 48; ++i) acc[i] = 0.f;
  for (int it = 0; it < 4; ++it){
    const int ll = it*64 + lane;
    float xv[32];
    #pragma unroll
    for (int c2 = 0; c2 < 16; ++c2){
      float2 t = xs2[ll*17 + c2];
      xv[2*c2] = t.x; xv[2*c2+1] = t.y;
    }
    float qq[8], kk[8];
    #pragma unroll
    for (int r = 0; r < 8; ++r){ qq[r] = 0.f; kk[r] = 0.f; }
    #pragma unroll
    for (int c = 0; c < 32; ++c){
      #pragma unroll
      for (int r = 0; r < 8; ++r){
        qq[r] = fmaf(Wq[r*32 + c], xv[c], qq[r]);
        kk[r] = fmaf(Wk[r*32 + c], xv[c], kk[r]);
      }
    }
    #pragma unroll
    for (int hh = 0; hh < 2; ++hh){
      const float* q = qq + hh*4;
      const float* k = kk + hh*4;
      const int base = hh*24;
      #pragma unroll
      for (int d = 0; d < 4; ++d){
        #pragma unroll
        for (int e = 0; e < 4; ++e)
          acc[base + d*4 + e] = fmaf(q[d], k[e], acc[base + d*4 + e]);
      }
      #pragma unroll
      for (int d = 0; d < 4; ++d) acc[base + 16 + d] = fmaf(q[d], q[d], acc[base + 16 + d]);
      #pragma unroll
      for (int e = 0; e < 4; ++e) acc[base + 20 + e] = fmaf(k[e], k[e], acc[base + 20 + e]);
    }
  }
  float* dst = xa_sums + b*192 + wave*48;
  int ch;
  float s0 = bfly32<false>(acc, lane, &ch);
  if (lane < 32) atomicAdd(dst + ch, s0);
  int ch2;
  float s1 = bfly16_sum(acc + 32, lane, &ch2);
  if (lane < 16) atomicAdd(dst + 32 + ch2, s1);
}

// ---------- K3b: fold XCA softmax into a single 32x32 matrix per b ----------
// f2 = Wp·(A·(Wv·x)) + bp == (Wp·A·Wv)·x + bp   ->  M2[b] = Wp·A·Wv
__global__ __launch_bounds__(64) void k_fold(const float* __restrict__ xa_sums,
                                             const float* __restrict__ temp,
                                             const float* __restrict__ Wqkv,
                                             const float* __restrict__ Wp,
                                             float* __restrict__ M2){
  __shared__ float attn_s[128];
  const int b = blockIdx.x, t = threadIdx.x;
  if (t < 32){
    const int h = t >> 2, d = t & 3;
    const float* xss = xa_sums + b*192 + h*24;
    const float tmp = temp[h];
    const float nq = fmaxf(sqrtf(xss[16 + d]), 1e-12f);
    float lg[4]; float m = -1e30f;
    #pragma unroll
    for (int e = 0; e < 4; ++e){
      float nk = fmaxf(sqrtf(xss[20 + e]), 1e-12f);
      lg[e] = xss[d*4 + e] * tmp / (nq*nk);
      m = fmaxf(m, lg[e]);
    }
    float Z = 0.f;
    #pragma unroll
    for (int e = 0; e < 4; ++e){ lg[e] = __expf(lg[e] - m); Z += lg[e]; }
    float iZ = 1.f/Z;
    #pragma unroll
    for (int e = 0; e < 4; ++e) attn_s[h*16 + d*4 + e] = lg[e]*iZ;
  }
  __syncthreads();
  if (t < 32){
    const int c = t;                          // column of M2
    const float* Wv = Wqkv + 64*32;
    float tmpv[32];                           // (A·Wv)[:, c]
    #pragma unroll
    for (int k = 0; k < 32; ++k){
      const int h = k >> 2, d = k & 3;
      float s = 0.f;
      #pragma unroll
      for (int e = 0; e < 4; ++e)
        s = fmaf(attn_s[h*16 + d*4 + e], Wv[(h*4 + e)*32 + c], s);
      tmpv[k] = s;
    }
    float out[32];
    #pragma unroll
    for (int r = 0; r < 32; ++r) out[r] = 0.f;
    #pragma unroll
    for (int k = 0; k < 32; ++k){
      #pragma unroll
      for (int r = 0; r < 32; ++r)
        out[r] = fmaf(Wp[r*32 + k], tmpv[k], out[r]);
    }
    #pragma unroll
    for (int r = 0; r < 32; ++r) M2[b*1024 + r*32 + c] = out[r];
  }
}

// ---------- K2: LA finalize -> f1, + fused channel sum/max stats ----------
// EXACT round-4 structure (measured 106us, VGPR 60, zero spill): split v-pass
// and per-head q-passes; merging them spills to scratch (round-5 regression).
__global__ __launch_bounds__(256, 4) void k_la_final(const float* __restrict__ rgb,
    const float* __restrict__ Wqkv, const float* __restrict__ la_attn,
    const float* __restrict__ dconv_w, const float* __restrict__ Wp,
    const float* __restrict__ bp, float* __restrict__ f1,
    float* __restrict__ sum1, unsigned* __restrict__ max1e){
  __shared__ float2 vsh2[264*17];        // 35.9 KB -> 4 blocks/CU
  const int b = blockIdx.y, l0 = blockIdx.x*256, tid = threadIdx.x;
  const int l = l0 + tid, lane = tid & 63;
  const float* xg = rgb + (size_t)b*CL;
  float x[32];
  #pragma unroll
  for (int c = 0; c < 32; ++c) x[c] = xg[c*LN + l];
  // own v -> conv tile (v dies after the LDS write; re-read own v from tile later)
  {
    float v[32];
    #pragma unroll
    for (int r = 0; r < 32; ++r) v[r] = 0.f;
    const float* Wv = Wqkv + 64*32;
    #pragma unroll
    for (int c = 0; c < 32; ++c){
      #pragma unroll
      for (int r = 0; r < 32; ++r) v[r] = fmaf(Wv[r*32 + c], x[c], v[r]);
    }
    #pragma unroll
    for (int c2 = 0; c2 < 16; ++c2)
      vsh2[(tid+4)*17 + c2] = make_float2(v[2*c2], v[2*c2+1]);
  }
  // halo v: 8 pixels x 16 float2-channels, one (p,c2) pair per thread (tid<128)
  if (tid < 128){
    const int p = tid >> 4, c2 = tid & 15;
    const int hl  = (p < 4) ? (l0 - 4 + p) : (l0 + 252 + p);
    const int pos = (p < 4) ? p : (256 + p);
    float2 vh = make_float2(0.f, 0.f);
    if (hl >= 0 && hl < LN){
      const float* W0 = Wqkv + (64 + 2*c2)*32;
      #pragma unroll 8
      for (int cc = 0; cc < 32; ++cc){
        float xv = xg[cc*LN + hl];
        vh.x = fmaf(W0[cc],      xv, vh.x);
        vh.y = fmaf(W0[32 + cc], xv, vh.y);
      }
    }
    vsh2[pos*17 + c2] = vh;
  }
  __syncthreads();
  float y[32];
  #pragma unroll
  for (int h = 0; h < 8; ++h){
    float q0 = 0.f, q1 = 0.f, q2 = 0.f, q3 = 0.f;
    const float* Wq = Wqkv + h*4*32;
    #pragma unroll
    for (int c = 0; c < 32; ++c){
      q0 = fmaf(Wq[c],      x[c], q0);
      q1 = fmaf(Wq[32 + c], x[c], q1);
      q2 = fmaf(Wq[64 + c], x[c], q2);
      q3 = fmaf(Wq[96 + c], x[c], q3);
    }
    const float rnq = rsqrtf(q0*q0 + q1*q1 + q2*q2 + q3*q3);
    q0 *= rnq; q1 *= rnq; q2 *= rnq; q3 *= rnq;
    const float* at = la_attn + b*128 + h*16;   // uniform -> s_load
    const float2 v01 = vsh2[(tid+4)*17 + h*2];
    const float2 v23 = vsh2[(tid+4)*17 + h*2 + 1];
    const float vo[4] = {v01.x, v01.y, v23.x, v23.y};
    float o[4]; float ss = 0.f;
    #pragma unroll
    for (int e = 0; e < 4; ++e){
      float t = 0.f;
      t = fmaf(q0, at[e],      t);
      t = fmaf(q1, at[4 + e],  t);
      t = fmaf(q2, at[8 + e],  t);
      t = fmaf(q3, at[12 + e], t);
      o[e] = fmaf(0.31830988618379067f, t, 0.5f*vo[e]);
      ss = fmaf(o[e], o[e], ss);
    }
    const float rno = rsqrtf(ss);
    float dc[4] = {0.f, 0.f, 0.f, 0.f};
    #pragma unroll
    for (int j = 0; j < 9; ++j){
      const float w = dconv_w[h*9 + j];
      const float2 p0 = vsh2[(tid + j)*17 + h*2];
      const float2 p1 = vsh2[(tid + j)*17 + h*2 + 1];
      dc[0] = fmaf(w, p0.x, dc[0]);
      dc[1] = fmaf(w, p0.y, dc[1]);
      dc[2] = fmaf(w, p1.x, dc[2]);
      dc[3] = fmaf(w, p1.y, dc[3]);
    }
    #pragma unroll
    for (int e = 0; e < 4; ++e) y[h*4 + e] = fmaf(o[e], rno, dc[e]);
  }
  // projection + stats
  float vals[32];
  float* f1p = f1 + (size_t)b*CL + l;
  #pragma unroll
  for (int r = 0; r < 32; ++r){
    float val = bp[r];
    #pragma unroll
    for (int c = 0; c < 32; ++c) val = fmaf(Wp[r*32 + c], y[c], val);
    f1p[r*LN] = val;
    vals[r] = val;
  }
  int ch;
  float s = bfly32<false>(vals, lane, &ch);
  float m = bfly32<true >(vals, lane, &ch);
  if (lane < 32){
    atomicAdd(&sum1[b*32 + ch], s);
    atomicMax(&max1e[b*32 + ch], fenc(m));
  }
}

// ---------- K4: XCA finalize -> f2 = M2[b]·x + bp, + fused stats ----------
__global__ __launch_bounds__(256, 4) void k_xa_final(const float* __restrict__ freq,
    const float* __restrict__ M2, const float* __restrict__ bp,
    float* __restrict__ f2, float* __restrict__ sum2, unsigned* __restrict__ max2e){
  const int b = blockIdx.y, l0 = blockIdx.x*256, tid = threadIdx.x;
  const int l = l0 + tid, lane = tid & 63;
  const float* xg = freq + (size_t)b*CL;
  float x[32];
  #pragma unroll
  for (int c = 0; c < 32; ++c) x[c] = xg[c*LN + l];
  const float* M = M2 + b*1024;            // uniform -> s_load
  float vals[32];
  #pragma unroll
  for (int r = 0; r < 32; ++r) vals[r] = bp[r];
  #pragma unroll
  for (int c = 0; c < 32; ++c){
    #pragma unroll
    for (int r = 0; r < 32; ++r) vals[r] = fmaf(M[r*32 + c], x[c], vals[r]);
  }
  float* f2p = f2 + (size_t)b*CL + l;
  #pragma unroll
  for (int r = 0; r < 32; ++r) f2p[r*LN] = vals[r];
  int ch;
  float s = bfly32<false>(vals, lane, &ch);
  float m = bfly32<true >(vals, lane, &ch);
  if (lane < 32){
    atomicAdd(&sum2[b*32 + ch], s);
    atomicMax(&max2e[b*32 + ch], fenc(m));
  }
}

// ---------- K5: channel vectors, cross softmax weights w1,w2 ----------
__global__ __launch_bounds__(64) void k_vec(
  const float* __restrict__ sum1, const unsigned* __restrict__ max1e,
  const float* __restrict__ sum2, const unsigned* __restrict__ max2e,
  const float* __restrict__ a1w, const float* __restrict__ a1b,
  const float* __restrict__ m1w, const float* __restrict__ m1b,
  const float* __restrict__ a2w, const float* __restrict__ a2b,
  const float* __restrict__ m2w, const float* __restrict__ m2b,
  const float* __restrict__ a11w, const float* __restrict__ a11b,
  const float* __restrict__ m11w, const float* __restrict__ m11b,
  const float* __restrict__ a22w, const float* __restrict__ a22b,
  const float* __restrict__ m22w, const float* __restrict__ m22b,
  float* __restrict__ w1o, float* __restrict__ w2o){
  __shared__ float avg1[32], mx1[32], avg2[32], mx2[32];
  __shared__ float h_a1[16], h_m1[16], h_a2[16], h_m2[16];
  __shared__ float a1v[32], a2v[32];
  const int b = blockIdx.x, t = threadIdx.x;
  if (t < 32){
    avg1[t] = sum1[b*32 + t] * (1.f/6400.f);
    mx1[t]  = fdec(max1e[b*32 + t]);
    avg2[t] = sum2[b*32 + t] * (1.f/6400.f);
    mx2[t]  = fdec(max2e[b*32 + t]);
  }
  __syncthreads();
  if (t < 16){
    float s1 = a1b[t], s2 = m1b[t], s3 = a2b[t], s4 = m2b[t];
    for (int c = 0; c < 32; ++c){
      s1 = fmaf(avg1[c], a1w[t*32 + c], s1);
      s2 = fmaf(mx1[c],  m1w[t*32 + c], s2);
      s3 = fmaf(avg2[c], a2w[t*32 + c], s3);
      s4 = fmaf(mx2[c],  m2w[t*32 + c], s4);
    }
    h_a1[t] = fmaxf(s1, 0.f); h_m1[t] = fmaxf(s2, 0.f);
    h_a2[t] = fmaxf(s3, 0.f); h_m2[t] = fmaxf(s4, 0.f);
  }
  __syncthreads();
  if (t < 32){
    float v1 = a11b[t] + m11b[t];
    float v2 = a22b[t] + m22b[t];
    for (int k = 0; k < 16; ++k){
      v1 += h_a1[k]*a11w[t*16 + k] + h_m1[k]*m11w[t*16 + k];
      v2 += h_a2[k]*a22w[t*16 + k] + h_m2[k]*m22w[t*16 + k];
    }
    a1v[t] = v1; a2v[t] = v2;
  }
  __syncthreads();
  if (t < 32){
    float s = a1v[t], m = -1e30f;
    for (int d = 0; d < 32; ++d) m = fmaxf(m, s*a2v[d]);
    float Z = 0.f;
    for (int d = 0; d < 32; ++d) Z += __expf(s*a2v[d] - m);
    float iZ = 1.f/Z;
    for (int d = 0; d < 32; ++d) w1o[b*1024 + t*32 + d] = __expf(s*a2v[d] - m)*iZ;
    float s2 = a2v[t]; m = -1e30f;
    for (int d = 0; d < 32; ++d) m = fmaxf(m, s2*a1v[d]);
    Z = 0.f;
    for (int d = 0; d < 32; ++d) Z += __expf(s2*a1v[d] - m);
    iZ = 1.f/Z;
    for (int d = 0; d < 32; ++d) w2o[b*1024 + t*32 + d] = __expf(s2*a1v[d] - m)*iZ;
  }
}

// ---------- K6: mixing + channel mean/max pooling (ILP accumulator form) ----------
__global__ __launch_bounds__(256, 4) void k_mix(const float* __restrict__ f1,
    const float* __restrict__ f2, const float* __restrict__ w1,
    const float* __restrict__ w2, float* __restrict__ pooled1,
    float* __restrict__ pooled2){
  const int b = blockIdx.y, l = blockIdx.x*256 + threadIdx.x;
  float fv[32], av[32];
  {
    const float* f1p = f1 + (size_t)b*CL + l;
    #pragma unroll
    for (int d = 0; d < 32; ++d) fv[d] = f1p[d*LN];
    const float* W = w1 + b*1024;
    #pragma unroll
    for (int c = 0; c < 32; ++c) av[c] = 0.f;
    #pragma unroll
    for (int d = 0; d < 32; ++d){
      #pragma unroll
      for (int c = 0; c < 32; ++c) av[c] = fmaf(W[c*32 + d], fv[d], av[c]);
    }
    float s = 0.f, m = -1e30f;
    #pragma unroll
    for (int c = 0; c < 32; ++c){ s += av[c]; m = fmaxf(m, av[c]); }
    pooled1[(size_t)b*2*LN + l]      = s*(1.f/32.f);
    pooled1[(size_t)b*2*LN + LN + l] = m;
  }
  {
    const float* f2p = f2 + (size_t)b*CL + l;
    #pragma unroll
    for (int d = 0; d < 32; ++d) fv[d] = f2p[d*LN];
    const float* W = w2 + b*1024;
    #pragma unroll
    for (int c = 0; c < 32; ++c) av[c] = 0.f;
    #pragma unroll
    for (int d = 0; d < 32; ++d){
      #pragma unroll
      for (int c = 0; c < 32; ++c) av[c] = fmaf(W[c*32 + d], fv[d], av[c]);
    }
    float s = 0.f, m = -1e30f;
    #pragma unroll
    for (int c = 0; c < 32; ++c){ s += av[c]; m = fmaxf(m, av[c]); }
    pooled2[(size_t)b*2*LN + l]      = s*(1.f/32.f);
    pooled2[(size_t)b*2*LN + LN + l] = m;
  }
}

// ---------- K7: conv3x3 -> relu -> conv3x3 -> softmax over L ----------
__global__ __launch_bounds__(256) void k_gate(const float* __restrict__ pooled1,
    const float* __restrict__ pooled2, const float* __restrict__ c1w,
    const float* __restrict__ c1b, const float* __restrict__ c2w,
    const float* __restrict__ c2b, float* __restrict__ g1, float* __restrict__ g2){
  __shared__ float y1s[6400];
  __shared__ float red[8];
  const int b = blockIdx.y, t = blockIdx.x, tid = threadIdx.x;
  const float* src = (t == 0 ? pooled1 : pooled2) + (size_t)b*2*LN;
  float* dst = (t == 0 ? g1 : g2) + (size_t)b*LN;
  for (int i = tid; i < 6400; i += 256){
    const int yy = i/80, xx = i - yy*80;
    float a = c1b[0];
    #pragma unroll
    for (int ky = 0; ky < 3; ++ky){
      const int y2 = yy + ky - 1;
      if (y2 < 0 || y2 >= 80) continue;
      #pragma unroll
      for (int kx = 0; kx < 3; ++kx){
        const int x2 = xx + kx - 1;
        if (x2 < 0 || x2 >= 80) continue;
        const int j = y2*80 + x2;
        a = fmaf(src[j],        c1w[ky*3 + kx],     a);
        a = fmaf(src[6400 + j], c1w[9 + ky*3 + kx], a);
      }
    }
    y1s[i] = fmaxf(a, 0.f);
  }
  __syncthreads();
  float y2r[25]; float lmax = -1e30f;
  #pragma unroll
  for (int ii = 0; ii < 25; ++ii){
    const int i = tid + ii*256;
    const int yy = i/80, xx = i - yy*80;
    float a = c2b[0];
    #pragma unroll
    for (int ky = 0; ky < 3; ++ky){
      const int y2 = yy + ky - 1;
      if (y2 < 0 || y2 >= 80) continue;
      #pragma unroll
      for (int kx = 0; kx < 3; ++kx){
        const int x2 = xx + kx - 1;
        if (x2 < 0 || x2 >= 80) continue;
        a = fmaf(y1s[y2*80 + x2], c2w[ky*3 + kx], a);
      }
    }
    y2r[ii] = a; lmax = fmaxf(lmax, a);
  }
  #pragma unroll
  for (int off = 32; off >= 1; off >>= 1) lmax = fmaxf(lmax, __shfl_xor(lmax, off, 64));
  if ((tid & 63) == 0) red[tid >> 6] = lmax;
  __syncthreads();
  const float bmax = fmaxf(fmaxf(red[0], red[1]), fmaxf(red[2], red[3]));
  float lsum = 0.f;
  #pragma unroll
  for (int ii = 0; ii < 25; ++ii){
    float e = __expf(y2r[ii] - bmax);
    y2r[ii] = e; lsum += e;
  }
  #pragma unroll
  for (int off = 32; off >= 1; off >>= 1) lsum += __shfl_xor(lsum, off, 64);
  if ((tid & 63) == 0) red[4 + (tid >> 6)] = lsum;
  __syncthreads();
  const float inv = 1.f/(red[4] + red[5] + red[6] + red[7]);
  #pragma unroll
  for (int ii = 0; ii < 25; ++ii) dst[tid + ii*256] = y2r[ii]*inv;
}

// ---------- K8: out = f1*(1+g1) + f2*(1+g2) ----------
__global__ __launch_bounds__(256) void k_final(const float* __restrict__ f1,
    const float* __restrict__ f2, const float* __restrict__ g1,
    const float* __restrict__ g2, float* __restrict__ out){
  const int i = blockIdx.x*256 + threadIdx.x;
  const int flat = i*4;
  const int b = flat / CL;
  const int rem = flat - b*CL;
  const int l = rem % LN;
  const float4 a  = *(const float4*)(f1 + flat);
  const float4 c  = *(const float4*)(f2 + flat);
  const float4 ga = *(const float4*)(g1 + b*LN + l);
  const float4 gc = *(const float4*)(g2 + b*LN + l);
  float4 o;
  o.x = fmaf(a.x, ga.x, a.x) + fmaf(c.x, gc.x, c.x);
  o.y = fmaf(a.y, ga.y, a.y) + fmaf(c.y, gc.y, c.y);
  o.z = fmaf(a.z, ga.z, a.z) + fmaf(c.z, gc.z, c.z);
  o.w = fmaf(a.w, ga.w, a.w) + fmaf(c.w, gc.w, c.w);
  *(float4*)(out + flat) = o;
}

// ---------- host ----------
extern "C" void kernel_launch(void* const* d_in, const int* in_sizes, int n_in,
                              void* d_out, int out_size, void* d_ws, size_t ws_size,
                              hipStream_t stream){
  const float* rgb     = (const float*)d_in[0];
  const float* freq    = (const float*)d_in[1];
  const float* la_qkv  = (const float*)d_in[2];
  const float* la_pw   = (const float*)d_in[3];
  const float* la_pb   = (const float*)d_in[4];
  const float* la_dw   = (const float*)d_in[5];
  const float* xa_qkv  = (const float*)d_in[6];
  const float* xa_temp = (const float*)d_in[7];
  const float* xa_pw   = (const float*)d_in[8];
  const float* xa_pb   = (const float*)d_in[9];
  const float* c1w     = (const float*)d_in[10];
  const float* c1b     = (const float*)d_in[11];
  const float* c2w     = (const float*)d_in[12];
  const float* c2b     = (const float*)d_in[13];

  float* ws = (float*)d_ws;
  size_t o = 0;
  float* f1      = ws + o; o += (size_t)BN*CL;
  float* f2      = ws + o; o += (size_t)BN*CL;
  float* la_attn = ws + o; o += BN*128;
  float* xa_sums = ws + o; o += BN*192;
  float* sum1    = ws + o; o += BN*32;
  unsigned* max1e = (unsigned*)(ws + o); o += BN*32;
  float* sum2    = ws + o; o += BN*32;
  unsigned* max2e = (unsigned*)(ws + o); o += BN*32;
  float* w1      = ws + o; o += BN*1024;
  float* w2      = ws + o; o += BN*1024;
  float* pooled1 = ws + o; o += (size_t)BN*2*LN;
  float* pooled2 = ws + o; o += (size_t)BN*2*LN;
  float* g1      = ws + o; o += (size_t)BN*LN;
  float* g2      = ws + o; o += (size_t)BN*LN;
  float* M2      = ws + o; o += (size_t)BN*1024;

  // zero the atomically-accumulated regions (la_attn .. max2e, contiguous)
  const size_t nz = (size_t)BN*128 + BN*192 + (size_t)BN*32*4;
  hipMemsetAsync(la_attn, 0, nz*sizeof(float), stream);

  k_la_reduce<<<dim3(25, BN), 256, 0, stream>>>(rgb, la_qkv, la_attn);
  k_xa_reduce<<<dim3(25, BN), 256, 0, stream>>>(freq, xa_qkv, xa_sums);
  k_fold     <<<BN, 64, 0, stream>>>(xa_sums, xa_temp, xa_qkv, xa_pw, M2);
  k_la_final <<<dim3(25, BN), 256, 0, stream>>>(rgb, la_qkv, la_attn, la_dw, la_pw, la_pb,
                                                f1, sum1, max1e);
  k_xa_final <<<dim3(25, BN), 256, 0, stream>>>(freq, M2, xa_pb, f2, sum2, max2e);
  k_vec<<<BN, 64, 0, stream>>>(sum1, max1e, sum2, max2e,
      (const float*)d_in[14], (const float*)d_in[15], (const float*)d_in[16], (const float*)d_in[17],
      (const float*)d_in[18], (const float*)d_in[19], (const float*)d_in[20], (const float*)d_in[21],
      (const float*)d_in[22], (const float*)d_in[23], (const float*)d_in[24], (const float*)d_in[25],
      (const float*)d_in[26], (const float*)d_in[27], (const float*)d_in[28], (const float*)d_in[29],
      w1, w2);
  k_mix  <<<dim3(25, BN), 256, 0, stream>>>(f1, f2, w1, w2, pooled1, pooled2);
  k_gate <<<dim3(2, BN), 256, 0, stream>>>(pooled1, pooled2, c1w, c1b, c2w, c2b, g1, g2);
  k_final<<<12800, 256, 0, stream>>>(f1, f2, g1, g2, (float*)d_out);
}